// Round 11
// baseline (877.850 us; speedup 1.0000x reference)
//
#include <hip/hip_runtime.h>
#include <math.h>

typedef __attribute__((ext_vector_type(8))) short short8;
typedef __attribute__((ext_vector_type(4))) float f32x4;

#define B_ 2
#define S_ 2048
#define D_ 1024
#define H_ 8
#define DH_ 128
#define NA_ 128
#define V_ 32000
#define MASKID_ 31999
#define Q_ 2048
#define KV_ 4096
#define KVP_ 4128
#define NROWS_ 4096
#define NRC_ 3840
#define NP_ 500

__device__ __forceinline__ float bf2f(ushort u){ union{uint u;float f;}v; v.u=(uint)u<<16; return v.f; }
__device__ __forceinline__ ushort f2bf(float f){ union{float f;uint u;}v; v.f=f; return (ushort)((v.u + 0x7fffu + ((v.u>>16)&1u))>>16); }

__device__ __forceinline__ f32x4 mfma16(short8 a, short8 b, f32x4 c){
  return __builtin_amdgcn_mfma_f32_16x16x32_bf16(a,b,c,0,0,0);
}
__device__ __forceinline__ float rmax16(float v){
  #pragma unroll
  for(int m=1;m<16;m<<=1) v = fmaxf(v, __shfl_xor(v,m));
  return v;
}
__device__ __forceinline__ float rsum16(float v){
  #pragma unroll
  for(int m=1;m<16;m<<=1) v += __shfl_xor(v,m);
  return v;
}

// ---------------- meta: draft ids / compact labels / positions ----------------
__global__ void k_meta(const int* __restrict__ ids, const int* __restrict__ anch,
                       int* __restrict__ draft, int* __restrict__ lab2, int* __restrict__ posf){
  int idx = blockIdx.x*256 + threadIdx.x;
  if (idx >= NROWS_) return;
  int b = idx >> 11, i = idx & (Q_-1);
  int p = i & 15;
  int a = anch[b*NA_ + (i>>4)];
  int pos = a + p;
  posf[idx] = pos;
  int gi = pos < S_ ? pos : S_-1;
  int tok = ids[b*S_ + gi];
  bool isa = (p==0);
  draft[idx] = isa ? tok : MASKID_;
  if (!isa){
    int rc = (idx >> 4)*15 + (p - 1);   // compact row index (pos always < S)
    lab2[rc] = tok;
  }
}

// ---------------- fused prep: hcat + weight converts + embedding gather ----------------
__global__ void k_prep(const float* __restrict__ hs,
    const float* __restrict__ fcw, const float* __restrict__ wq, const float* __restrict__ wk,
    const float* __restrict__ wv, const float* __restrict__ wo, const float* __restrict__ lmw,
    const float* __restrict__ et, const int* __restrict__ ids, const int* __restrict__ anch,
    ushort* __restrict__ hc, ushort* __restrict__ fcW, ushort* __restrict__ Wqkv,
    ushort* __restrict__ woW, ushort* __restrict__ lmW, ushort* __restrict__ emb){
  int idx = blockIdx.x*256 + threadIdx.x;
  const float* src; ushort* dst; size_t so, doff;
  if (idx < 1572864){
    int f8 = idx % 384; int row = idx / 384;
    int b = row >> 11, s = row & (S_-1);
    int f0 = f8*8, l = f0 >> 10, d = f0 & 1023;
    src = hs; so = (((size_t)l*B_ + b)*S_ + s)*D_ + d;
    dst = hc; doff = (size_t)row*3072 + f0;
  } else if (idx < 6586368){
    int i = idx - 1572864;
    int j;
    if (i < 393216){ src = fcw; dst = fcW; j = i; }
    else if (i < 524288){ src = wq;  dst = Wqkv;                    j = i - 393216; }
    else if (i < 655360){ src = wk;  dst = Wqkv + (size_t)1048576;  j = i - 524288; }
    else if (i < 786432){ src = wv;  dst = Wqkv + (size_t)2097152;  j = i - 655360; }
    else if (i < 917504){ src = wo;  dst = woW;                     j = i - 786432; }
    else               { src = lmw; dst = lmW;                     j = i - 917504; }
    so = (size_t)j*8; doff = (size_t)j*8;
  } else if (idx < 7110656){
    int j = idx - 6586368;
    int row = j >> 7, c = (j & 127)*8;
    int b = row >> 11, i = row & (Q_-1);
    int p = i & 15;
    int a = anch[b*NA_ + (i>>4)];
    int pos = a + p;
    int gi = pos < S_ ? pos : S_-1;
    int tok = ids[b*S_ + gi];
    int id = (p==0) ? tok : MASKID_;
    src = et; so = (size_t)id*D_ + c;
    dst = emb; doff = (size_t)row*D_ + c;
  } else return;
  const float4* s4 = (const float4*)(src + so);
  float4 a = s4[0], b = s4[1];
  short8 u;
  u[0]=(short)f2bf(a.x); u[1]=(short)f2bf(a.y); u[2]=(short)f2bf(a.z); u[3]=(short)f2bf(a.w);
  u[4]=(short)f2bf(b.x); u[5]=(short)f2bf(b.y); u[6]=(short)f2bf(b.z); u[7]=(short)f2bf(b.w);
  *(short8*)(dst + doff) = u;
}

// ---------------- shared GEMM body: C(128x128 tile) = A(MxK) * B(NxK)^T ----------------
__device__ __forceinline__ void gemm_body(const ushort* __restrict__ A, const ushort* __restrict__ Bm,
    void* __restrict__ C, int N, int K, int bm, int bn, int OBF, ushort* lA, ushort* lB){
  const int lane = threadIdx.x & 63, w = threadIdx.x >> 6;
  const int l15 = lane & 15, g = lane >> 4;
  const int wm = w >> 1, wn = w & 1;
  f32x4 acc[4][4];
  #pragma unroll
  for (int a0=0;a0<4;++a0)
    #pragma unroll
    for (int a1=0;a1<4;++a1) acc[a0][a1] = f32x4{0.f,0.f,0.f,0.f};
  int rowS[2], kgS[2];
  #pragma unroll
  for (int i=0;i<2;++i){
    int o = w*1024 + i*4096 + lane*16;
    rowS[i] = o >> 6;
    kgS[i] = (((o>>4)&3) - (rowS[i]>>1)) & 3;
  }
  for (int k0 = 0; k0 < K; k0 += 32){
    #pragma unroll
    for (int i=0;i<2;++i){
      const ushort* sa = A + (size_t)(bm*128 + rowS[i])*K + k0 + kgS[i]*8;
      const ushort* sb = Bm + (size_t)(bn*128 + rowS[i])*K + k0 + kgS[i]*8;
      __builtin_amdgcn_global_load_lds((const __attribute__((address_space(1))) void*)sa,
          (__attribute__((address_space(3))) void*)((char*)lA + w*1024 + i*4096), 16, 0, 0);
      __builtin_amdgcn_global_load_lds((const __attribute__((address_space(1))) void*)sb,
          (__attribute__((address_space(3))) void*)((char*)lB + w*1024 + i*4096), 16, 0, 0);
    }
    __syncthreads();
    short8 af[4], bf[4];
    #pragma unroll
    for (int mf=0;mf<4;++mf){
      int rr = wm*64 + mf*16 + l15;
      af[mf] = *(const short8*)((const char*)lA + rr*64 + (((g + (rr>>1))&3)*16));
    }
    #pragma unroll
    for (int nf=0;nf<4;++nf){
      int rr = wn*64 + nf*16 + l15;
      bf[nf] = *(const short8*)((const char*)lB + rr*64 + (((g + (rr>>1))&3)*16));
    }
    #pragma unroll
    for (int mf=0;mf<4;++mf)
      #pragma unroll
      for (int nf=0;nf<4;++nf)
        acc[mf][nf] = mfma16(af[mf], bf[nf], acc[mf][nf]);
    __syncthreads();
  }
  #pragma unroll
  for (int mf=0;mf<4;++mf)
  #pragma unroll
  for (int nf=0;nf<4;++nf){
    int row0 = bm*128 + wm*64 + mf*16 + g*4;
    int col  = bn*128 + wn*64 + nf*16 + l15;
    #pragma unroll
    for (int r=0;r<4;++r){
      if (OBF) ((ushort*)C)[(size_t)(row0+r)*N + col] = f2bf(acc[mf][nf][r]);
      else     ((float*)C)[(size_t)(row0+r)*N + col] = acc[mf][nf][r];
    }
  }
}

template<int OBF>
__global__ __launch_bounds__(256) void k_gemm(const ushort* __restrict__ A, const ushort* __restrict__ Bm,
                       void* __restrict__ C, int N, int K){
  __shared__ ushort lA[128*32];
  __shared__ ushort lB[128*32];
  gemm_body(A, Bm, C, N, K, blockIdx.x, blockIdx.y, OBF, lA, lB);
}

// fc GEMM (256 blocks) + qkv GEMM (768 blocks) merged: balanced (256*96 == 768*32 iters)
__global__ __launch_bounds__(256) void k_fcqkv(const ushort* __restrict__ hcat, const ushort* __restrict__ fcW,
    ushort* __restrict__ ctx, const ushort* __restrict__ emb, const ushort* __restrict__ Wqkv,
    ushort* __restrict__ C1){
  __shared__ ushort lA[128*32];
  __shared__ ushort lB[128*32];
  int bid = blockIdx.x;
  if (bid < 256){
    gemm_body(hcat, fcW, ctx, 1024, 3072, bid & 31, bid >> 5, 1, lA, lB);
  } else {
    int t = bid - 256;
    gemm_body(emb, Wqkv, C1, 3072, 1024, t & 31, t >> 5, 1, lA, lB);
  }
}

// ---------------- lm_head bf16 GEMM, BK=64 dual-plane, fused softmax/argmax ----------------
// Each LDS matrix = two 8 KB planes (k-lo/k-hi); each plane is the PROVEN 0-conflict
// slot-rotation geometry (64-B rows, rotate (s+(rr>>1))&3, inverse on global source).
// One barrier pair per 64 K (32 MFMA) -> half the drain count of the r6 structure.
__global__ __launch_bounds__(256) void k_lmgemm(const ushort* __restrict__ A, const ushort* __restrict__ Bm,
    float* __restrict__ pm, float* __restrict__ pl, int* __restrict__ pbi){
  __shared__ ushort lA[128*64];   // 16 KB = 2 planes
  __shared__ ushort lB[128*64];
  const int bm = blockIdx.x, bn = blockIdx.y;
  if (bm >= 30) return;
  const int lane = threadIdx.x & 63, w = threadIdx.x >> 6;
  const int l15 = lane & 15, g = lane >> 4;
  const int wm = w >> 1, wn = w & 1;
  f32x4 acc[4][4];
  #pragma unroll
  for (int a0=0;a0<4;++a0)
    #pragma unroll
    for (int a1=0;a1<4;++a1) acc[a0][a1] = f32x4{0.f,0.f,0.f,0.f};
  int srcO[4];
  #pragma unroll
  for (int i=0;i<4;++i){
    int o = w*1024 + i*4096 + lane*16;
    int p = o >> 13, o2 = o & 8191;
    int r = o2 >> 6;
    int kg = (((o2>>4)&3) - (r>>1)) & 3;
    srcO[i] = r*1024 + p*32 + kg*8;     // row*K + plane-k + slot-k (K=1024)
  }
  const ushort* Ab = A + (size_t)bm*128*1024;
  const ushort* Bb = Bm + (size_t)bn*128*1024;
  for (int k0 = 0; k0 < 1024; k0 += 64){
    #pragma unroll
    for (int i=0;i<4;++i){
      __builtin_amdgcn_global_load_lds((const __attribute__((address_space(1))) void*)(Ab + k0 + srcO[i]),
          (__attribute__((address_space(3))) void*)((char*)lA + w*1024 + i*4096), 16, 0, 0);
      __builtin_amdgcn_global_load_lds((const __attribute__((address_space(1))) void*)(Bb + k0 + srcO[i]),
          (__attribute__((address_space(3))) void*)((char*)lB + w*1024 + i*4096), 16, 0, 0);
    }
    __syncthreads();
    #pragma unroll
    for (int pl2=0; pl2<2; ++pl2){
      const char* bA = (const char*)lA + pl2*8192;
      const char* bB = (const char*)lB + pl2*8192;
      short8 af[4], bfr[4];
      #pragma unroll
      for (int mf=0;mf<4;++mf){
        int rr = wm*64 + mf*16 + l15;
        af[mf] = *(const short8*)(bA + rr*64 + (((g + (rr>>1))&3)*16));
      }
      #pragma unroll
      for (int nf=0;nf<4;++nf){
        int rr = wn*64 + nf*16 + l15;
        bfr[nf] = *(const short8*)(bB + rr*64 + (((g + (rr>>1))&3)*16));
      }
      #pragma unroll
      for (int mf=0;mf<4;++mf)
        #pragma unroll
        for (int nf=0;nf<4;++nf)
          acc[mf][nf] = mfma16(af[mf], bfr[nf], acc[mf][nf]);
    }
    __syncthreads();
  }
  // epilogue: per-row stats over this wave's 64 columns; slice = bn*2+wn
  const int colb = bn*128 + wn*64 + l15;
  #pragma unroll
  for (int mf=0;mf<4;++mf){
    #pragma unroll
    for (int r=0;r<4;++r){
      float s0 = acc[mf][0][r], s1 = acc[mf][1][r], s2 = acc[mf][2][r], s3 = acc[mf][3][r];
      float M = rmax16(fmaxf(fmaxf(s0,s1), fmaxf(s2,s3)));
      float lsum = rsum16(__expf(s0-M) + __expf(s1-M) + __expf(s2-M) + __expf(s3-M));
      int ci = 0x7fffffff;
      if (s3 == M) ci = colb+48;
      if (s2 == M) ci = colb+32;
      if (s1 == M) ci = colb+16;
      if (s0 == M) ci = colb;
      #pragma unroll
      for (int msk=1; msk<16; msk<<=1){
        int oi = __shfl_xor(ci, msk);
        ci = oi < ci ? oi : ci;
      }
      if (l15 == 0){
        int row = bm*128 + wm*64 + mf*16 + g*4 + r;
        size_t pidx = (size_t)(bn*2 + wn)*NRC_ + row;
        pm[pidx] = M; pl[pidx] = lsum; pbi[pidx] = ci;
      }
    }
  }
}

// ---------------- fused RoPE scatter (draft + ctx) and vT pad-zero ----------------
__global__ void k_ropeall(const ushort* __restrict__ C1, const ushort* __restrict__ C2,
    const int* __restrict__ posf, ushort* __restrict__ qb, ushort* __restrict__ kb,
    ushort* __restrict__ vT){
  int idx = blockIdx.x*256 + threadIdx.x;
  if (idx < 2097152){
    int d2 = idx & 63, h = (idx>>6)&7, i = (idx>>9)&(Q_-1), b = idx>>20;
    int row = b*Q_ + i;
    int pos = posf[row];
    float inv = __expf(-(float)d2 * 0.14391156831212787f); // ln(10000)/64
    float ang = (float)pos * inv;
    float sn, cs; __sincosf(ang, &sn, &cs);
    const ushort* cr = C1 + (size_t)row*3072 + h*DH_ + d2;
    float x1 = bf2f(cr[0]), x2 = bf2f(cr[64]);
    size_t qo = (size_t)row*D_ + h*DH_ + d2;
    qb[qo] = f2bf(x1*cs - x2*sn); qb[qo+64] = f2bf(x1*sn + x2*cs);
    x1 = bf2f(cr[1024]); x2 = bf2f(cr[1088]);
    size_t ko = ((size_t)(b*KV_ + S_ + i))*D_ + h*DH_ + d2;
    kb[ko] = f2bf(x1*cs - x2*sn); kb[ko+64] = f2bf(x1*sn + x2*cs);
    x1 = bf2f(cr[2048]); x2 = bf2f(cr[2112]);
    size_t vo = ((size_t)((b*H_ + h)*DH_ + d2))*KVP_ + (S_ + i);
    vT[vo] = f2bf(x1); vT[vo + (size_t)64*KVP_] = f2bf(x2);
  } else if (idx < 4194304){
    int t = idx - 2097152;
    int d2 = t & 63, h = (t>>6)&7, i = (t>>9)&(S_-1), b = t>>20;
    int row = b*S_ + i;
    float inv = __expf(-(float)d2 * 0.14391156831212787f);
    float ang = (float)i * inv;
    float sn, cs; __sincosf(ang, &sn, &cs);
    const ushort* cr = C2 + (size_t)row*2048 + h*DH_ + d2;
    float x1 = bf2f(cr[0]), x2 = bf2f(cr[64]);
    size_t ko = ((size_t)(b*KV_ + i))*D_ + h*DH_ + d2;
    kb[ko] = f2bf(x1*cs - x2*sn); kb[ko+64] = f2bf(x1*sn + x2*cs);
    x1 = bf2f(cr[1024]); x2 = bf2f(cr[1088]);
    size_t vo = ((size_t)((b*H_ + h)*DH_ + d2))*KVP_ + i;
    vT[vo] = f2bf(x1); vT[vo + (size_t)64*KVP_] = f2bf(x2);
  } else if (idx < 4259840){
    int t = idx - 4194304;
    int row = t >> 5, c = t & 31;
    vT[(size_t)row*KVP_ + 4096 + c] = 0;
  }
}

// ---------------- block-sparse flash attention, split-KV, KVBLK=64 ----------------
__global__ __launch_bounds__(512) void k_attn(const ushort* __restrict__ qb, const ushort* __restrict__ kb,
    const ushort* __restrict__ vT, const int* __restrict__ anch, ushort* __restrict__ ao){
  __shared__ ushort pbuf[8][16*72];
  __shared__ float mrg[4][16][128];
  __shared__ float mml[4][2][16];
  const int lane = threadIdx.x & 63, w = threadIdx.x >> 6;
  const int l15 = lane & 15, g = lane >> 4;
  const int wt = w & 3, half = w >> 2;
  const int gi = blockIdx.x;
  const int logical = (gi & 7)*64 + (gi >> 3);   // bijective XCD grouping (512 blocks)
  const int b = logical >> 8, h = (logical >> 5) & 7;
  const int qblk = (logical & 31)*4 + wt;
  const int anc = anch[b*NA_ + qblk];
  ushort* pb = pbuf[w];
  short8 aq[4];
  {
    const ushort* qr = qb + ((size_t)(b*Q_ + qblk*16 + l15))*D_ + h*DH_ + g*8;
    #pragma unroll
    for (int kc=0;kc<4;++kc) aq[kc] = *(const short8*)(qr + kc*32);
  }
  f32x4 o[8];
  #pragma unroll
  for (int cc=0;cc<8;++cc) o[cc] = f32x4{0.f,0.f,0.f,0.f};
  float m[4] = {-1e30f,-1e30f,-1e30f,-1e30f};
  float sl[4] = {0.f,0.f,0.f,0.f};
  const float SC = 0.08838834764831845f; // 1/sqrt(128)
  const ushort* vbase = vT + ((size_t)((b*H_ + h)*DH_))*KVP_;

  auto process = [&](int kv0, int limit){
    const int nk = limit - kv0;
    f32x4 sc[4];
    #pragma unroll
    for (int f=0;f<4;++f) sc[f] = f32x4{0.f,0.f,0.f,0.f};
    const ushort* kr = kb + ((size_t)(b*KV_ + kv0 + l15))*D_ + h*DH_ + g*8;
    #pragma unroll
    for (int f=0;f<4;++f){
      if (f*16 < nk){
        const ushort* krf = kr + (size_t)(f*16)*D_;
        #pragma unroll
        for (int kc=0;kc<4;++kc){
          short8 bk = *(const short8*)(krf + kc*32);
          sc[f] = mfma16(aq[kc], bk, sc[f]);
        }
      }
    }
    #pragma unroll
    for (int r=0;r<4;++r){
      float s0 = (kv0 + l15      < limit) ? sc[0][r]*SC : -1e30f;
      float s1 = (kv0 + 16 + l15 < limit) ? sc[1][r]*SC : -1e30f;
      float s2 = (kv0 + 32 + l15 < limit) ? sc[2][r]*SC : -1e30f;
      float s3 = (kv0 + 48 + l15 < limit) ? sc[3][r]*SC : -1e30f;
      float cm = rmax16(fmaxf(fmaxf(s0,s1), fmaxf(s2,s3)));
      float mn = fmaxf(m[r], cm);
      float esc = __expf(m[r] - mn);
      float p0 = __expf(s0 - mn), p1 = __expf(s1 - mn);
      float p2 = __expf(s2 - mn), p3 = __expf(s3 - mn);
      float rs = rsum16(p0 + p1 + p2 + p3);
      sl[r] = sl[r]*esc + rs;
      m[r] = mn;
      #pragma unroll
      for (int cc=0;cc<8;++cc) o[cc][r] *= esc;
      int q = g*4 + r;
      pb[q*72 + l15]      = f2bf(p0);
      pb[q*72 + 16 + l15] = f2bf(p1);
      pb[q*72 + 32 + l15] = f2bf(p2);
      pb[q*72 + 48 + l15] = f2bf(p3);
    }
    asm volatile("s_waitcnt lgkmcnt(0)" ::: "memory");
    __builtin_amdgcn_sched_barrier(0);
    const ushort* pr = pb + l15*72 + g*8;
    short8 pa0 = *(const short8*)pr;
    const ushort* vr = vbase + kv0 + g*8;
    #pragma unroll
    for (int cc=0;cc<8;++cc){
      short8 bv = *(const short8*)(vr + (size_t)(cc*16 + l15)*KVP_);
      o[cc] = mfma16(pa0, bv, o[cc]);
    }
    if (nk > 32){
      short8 pa1 = *(const short8*)(pr + 32);
      const ushort* vr2 = vr + 32;
      #pragma unroll
      for (int cc=0;cc<8;++cc){
        short8 bv = *(const short8*)(vr2 + (size_t)(cc*16 + l15)*KVP_);
        o[cc] = mfma16(pa1, bv, o[cc]);
      }
    }
  };
  for (int kv0 = half*64; kv0 < anc; kv0 += 128) process(kv0, anc);
  if (half == 1){
    int kv0 = S_ + qblk*16;
    process(kv0, kv0 + 16);
    #pragma unroll
    for (int cc=0;cc<8;++cc)
      #pragma unroll
      for (int r=0;r<4;++r)
        mrg[wt][g*4+r][cc*16+l15] = o[cc][r];
    if (l15 == 0){
      #pragma unroll
      for (int r=0;r<4;++r){ mml[wt][0][g*4+r] = m[r]; mml[wt][1][g*4+r] = sl[r]; }
    }
  }
  __syncthreads();
  if (half == 0){
    #pragma unroll
    for (int r=0;r<4;++r){
      float m1 = mml[wt][0][g*4+r], l1 = mml[wt][1][g*4+r];
      float mn = fmaxf(m[r], m1);
      float e0 = __expf(m[r] - mn), e1 = __expf(m1 - mn);
      float lm = sl[r]*e0 + l1*e1;
      int q = g*4 + r;
      #pragma unroll
      for (int cc=0;cc<8;++cc){
        float val = (o[cc][r]*e0 + mrg[wt][q][cc*16+l15]*e1) / lm;
        ao[((size_t)(b*Q_ + qblk*16 + q))*D_ + h*DH_ + cc*16 + l15] = f2bf(val);
      }
    }
  }
}

// ---------------- residual + RMSNorm -> compact hb + fused label logit ----------------
__global__ __launch_bounds__(256) void k_rms(const float* __restrict__ wo_out, const float* __restrict__ et,
    const int* __restrict__ draft, const float* __restrict__ nw, const int* __restrict__ lab2,
    const float* __restrict__ lmw, ushort* __restrict__ hb, float* __restrict__ plbl){
  const int rc = blockIdx.x, tid = threadIdx.x;
  const int row = (rc/15)*16 + rc%15 + 1;     // inverse compact map (p = rc%15+1)
  const int lane = tid & 63, w = tid >> 6;
  const float* wr = wo_out + (size_t)row*D_;
  const float* er = et + (size_t)draft[row]*D_;
  float v[4]; float ss = 0.f;
  #pragma unroll
  for (int j=0;j<4;++j){
    int d = tid + j*256;
    v[j] = er[d] + wr[d];
    ss += v[j]*v[j];
  }
  #pragma unroll
  for (int msk=1; msk<64; msk<<=1) ss += __shfl_xor(ss, msk);
  __shared__ float red[4];
  __shared__ float red2[4];
  if (lane == 0) red[w] = ss;
  __syncthreads();
  float tot = red[0]+red[1]+red[2]+red[3];
  float rs = rsqrtf(tot*(1.f/1024.f) + 1e-6f);
  const float* lr = lmw + (size_t)lab2[rc]*D_;
  float sdot = 0.f;
  #pragma unroll
  for (int j=0;j<4;++j){
    int d = tid + j*256;
    float x = v[j]*rs*nw[d];
    hb[(size_t)rc*D_ + d] = f2bf(x);
    sdot += x * lr[d];
  }
  #pragma unroll
  for (int msk=1; msk<64; msk<<=1) sdot += __shfl_xor(sdot, msk);
  if (lane == 0) red2[w] = sdot;
  __syncthreads();
  if (tid == 0) plbl[rc] = red2[0]+red2[1]+red2[2]+red2[3];
}

// ---------------- combine: one wave per compact row, lane-strided over NP_ slices ----------------
__global__ __launch_bounds__(256) void k_combine(const float* __restrict__ pm, const float* __restrict__ pl,
    const int* __restrict__ pbi, const float* __restrict__ plbl,
    const int* __restrict__ lab2, float* __restrict__ pblk){
  const int lane = threadIdx.x & 63, w = threadIdx.x >> 6;
  const int row = blockIdx.x*4 + w;
  float M = -1e30f, Lx = 0.f;
  float bv = -1e30f; int bi = 0x7fffffff;
  for (int s = lane; s < NP_; s += 64){
    size_t idx = (size_t)s*NRC_ + row;
    float mm = pm[idx], ll = pl[idx];
    float Mn = fmaxf(M, mm);
    Lx = Lx*__expf(M-Mn) + ll*__expf(mm-Mn);
    M = Mn;
    int ii = pbi[idx];
    if (mm > bv || (mm == bv && ii < bi)){ bv = mm; bi = ii; }
  }
  #pragma unroll
  for (int msk=1; msk<64; msk<<=1){
    float Mo = __shfl_xor(M, msk), Lo = __shfl_xor(Lx, msk);
    float bvo = __shfl_xor(bv, msk); int bio = __shfl_xor(bi, msk);
    float Mn = fmaxf(M, Mo);
    Lx = Lx*__expf(M-Mn) + Lo*__expf(Mo-Mn);
    M = Mn;
    if (bvo > bv || (bvo == bv && bio < bi)){ bv = bvo; bi = bio; }
  }
  __shared__ float red[4][4];
  if (lane == 0){
    float logZ = M + logf(Lx);
    float lb = plbl[row];
    int lab = lab2[row];
    float wgt = __expf(-(float)(row%15)*(1.f/7.f));   // p = row%15+1
    float nll = logZ - lb;
    red[w][0] = wgt*nll;
    red[w][1] = wgt;
    red[w][2] = (bi == lab) ? 1.f : 0.f;
    red[w][3] = 1.f;
  }
  __syncthreads();
  if (threadIdx.x == 0){
    float s0=0,s1=0,s2=0,s3=0;
    for (int i=0;i<4;++i){ s0+=red[i][0]; s1+=red[i][1]; s2+=red[i][2]; s3+=red[i][3]; }
    pblk[blockIdx.x*4+0]=s0; pblk[blockIdx.x*4+1]=s1; pblk[blockIdx.x*4+2]=s2; pblk[blockIdx.x*4+3]=s3;
  }
}

__global__ void k_final(const float* __restrict__ pblk, float* __restrict__ out){
  const int t = threadIdx.x;
  float s0=0,s1=0,s2=0,s3=0;
  for (int i=t; i<960; i+=256){
    const float4 v = *(const float4*)(pblk + i*4);
    s0+=v.x; s1+=v.y; s2+=v.z; s3+=v.w;
  }
  #pragma unroll
  for (int msk=1; msk<64; msk<<=1){
    s0+=__shfl_xor(s0,msk); s1+=__shfl_xor(s1,msk);
    s2+=__shfl_xor(s2,msk); s3+=__shfl_xor(s3,msk);
  }
  __shared__ float red[4][4];
  int lane = t & 63, w = t >> 6;
  if (lane==0){ red[w][0]=s0; red[w][1]=s1; red[w][2]=s2; red[w][3]=s3; }
  __syncthreads();
  if (t==0){
    float a0=red[0][0]+red[1][0]+red[2][0]+red[3][0];
    float a1=red[0][1]+red[1][1]+red[2][1]+red[3][1];
    float a2=red[0][2]+red[1][2]+red[2][2]+red[3][2];
    float a3=red[0][3]+red[1][3]+red[2][3]+red[3][3];
    out[0]=a0/fmaxf(a1,1e-6f);
    out[1]=a2/fmaxf(a3,1.f);
  }
}

extern "C" void kernel_launch(void* const* d_in, const int* in_sizes, int n_in,
                              void* d_out, int out_size, void* d_ws, size_t ws_size,
                              hipStream_t stream){
  const int*   ids  = (const int*)d_in[0];
  const float* hs   = (const float*)d_in[1];
  const int*   anch = (const int*)d_in[2];
  const float* lmw  = (const float*)d_in[3];
  const float* nw   = (const float*)d_in[4];
  const float* fcw  = (const float*)d_in[5];
  const float* et   = (const float*)d_in[6];
  const float* wq   = (const float*)d_in[7];
  const float* wk   = (const float*)d_in[8];
  const float* wvp  = (const float*)d_in[9];
  const float* wo   = (const float*)d_in[10];
  float* out = (float*)d_out;
  (void)in_sizes; (void)n_in; (void)out_size; (void)ws_size;

  char* ws = (char*)d_ws;
  size_t off = 0;
  auto alloc = [&](size_t bytes)->char*{ char* p = ws + off; off = (off + bytes + 255) & ~(size_t)255; return p; };
  ushort* fcW   = (ushort*)alloc((size_t)1024*3072*2);
  ushort* Wqkv  = (ushort*)alloc((size_t)3072*1024*2);
  ushort* woW   = (ushort*)alloc((size_t)1024*1024*2);
  ushort* lmW   = (ushort*)alloc((size_t)V_*1024*2);
  ushort* ctx   = (ushort*)alloc((size_t)4096*1024*2);   // later: pm overlay (7.68MB)
  ushort* emb   = (ushort*)alloc((size_t)4096*1024*2);   // later: pl overlay
  ushort* hcat  = (ushort*)alloc((size_t)4096*3072*2);   // reused as C1, later pbi overlay
  ushort* C1 = hcat;
  ushort* C2    = (ushort*)alloc((size_t)4096*2048*2);   // reused as wo_out (f32)
  float* wo_out = (float*)C2;
  ushort* qbuf  = (ushort*)alloc((size_t)4096*1024*2);
  ushort* kbuf  = (ushort*)alloc((size_t)B_*KV_*1024*2);
  ushort* vT    = (ushort*)alloc((size_t)B_*H_*DH_*KVP_*2);
  ushort* ao    = (ushort*)alloc((size_t)4096*1024*2);
  ushort* hb    = (ushort*)alloc((size_t)NRC_*1024*2);
  int* draft  = (int*)alloc(4096*4);
  int* lab2   = (int*)alloc(NRC_*4);
  int* posf   = (int*)alloc(4096*4);
  float* plbl = (float*)alloc(NRC_*4);
  float* pblk = (float*)alloc(960*4*4);
  // partial arrays (each NP_*NRC_*4 = 7.68 MB) overlay buffers dead by lm_head time,
  // fully rewritten by k_lmgemm every call (tripwire-safe: no stale reads possible)
  float* pm  = (float*)ctx;
  float* pl  = (float*)emb;
  int*   pbi = (int*)hcat;

  k_meta<<<16,256,0,stream>>>(ids, anch, draft, lab2, posf);
  k_prep<<<27776,256,0,stream>>>(hs, fcw, wq, wk, wvp, wo, lmw, et, ids, anch,
                                 hcat, fcW, Wqkv, woW, lmW, emb);
  k_fcqkv<<<1024,256,0,stream>>>(hcat, fcW, ctx, emb, Wqkv, C1);
  k_gemm<1><<<dim3(32,16),256,0,stream>>>(ctx, Wqkv + (size_t)1024*1024, C2, 2048, 1024);
  k_ropeall<<<16640,256,0,stream>>>(C1, C2, posf, qbuf, kbuf, vT);
  k_attn<<<512,512,0,stream>>>(qbuf, kbuf, vT, anch, ao);
  k_gemm<0><<<dim3(32,8),256,0,stream>>>(ao, woW, wo_out, 1024, 1024);
  k_rms<<<NRC_,256,0,stream>>>(wo_out, et, draft, nw, lab2, lmw, hb, plbl);
  k_lmgemm<<<dim3(32,250),256,0,stream>>>(hb, lmW, pm, pl, pbi);
  k_combine<<<960,256,0,stream>>>(pm, pl, pbi, plbl, lab2, pblk);
  k_final<<<1,256,0,stream>>>(pblk, out);
}

// Round 12
// 795.397 us; speedup vs baseline: 1.1037x; 1.1037x over previous
//
#include <hip/hip_runtime.h>
#include <math.h>

typedef __attribute__((ext_vector_type(8))) short short8;
typedef __attribute__((ext_vector_type(4))) float f32x4;

#define B_ 2
#define S_ 2048
#define D_ 1024
#define H_ 8
#define DH_ 128
#define NA_ 128
#define V_ 32000
#define MASKID_ 31999
#define Q_ 2048
#define KV_ 4096
#define KVP_ 4128
#define NROWS_ 4096
#define NRC_ 3840
#define NP_ 500

__device__ __forceinline__ float bf2f(ushort u){ union{uint u;float f;}v; v.u=(uint)u<<16; return v.f; }
__device__ __forceinline__ ushort f2bf(float f){ union{float f;uint u;}v; v.f=f; return (ushort)((v.u + 0x7fffu + ((v.u>>16)&1u))>>16); }

__device__ __forceinline__ f32x4 mfma16(short8 a, short8 b, f32x4 c){
  return __builtin_amdgcn_mfma_f32_16x16x32_bf16(a,b,c,0,0,0);
}
__device__ __forceinline__ float rmax16(float v){
  #pragma unroll
  for(int m=1;m<16;m<<=1) v = fmaxf(v, __shfl_xor(v,m));
  return v;
}
__device__ __forceinline__ float rsum16(float v){
  #pragma unroll
  for(int m=1;m<16;m<<=1) v += __shfl_xor(v,m);
  return v;
}

// ---------------- meta: draft ids / compact labels / positions ----------------
__global__ void k_meta(const int* __restrict__ ids, const int* __restrict__ anch,
                       int* __restrict__ draft, int* __restrict__ lab2, int* __restrict__ posf){
  int idx = blockIdx.x*256 + threadIdx.x;
  if (idx >= NROWS_) return;
  int b = idx >> 11, i = idx & (Q_-1);
  int p = i & 15;
  int a = anch[b*NA_ + (i>>4)];
  int pos = a + p;
  posf[idx] = pos;
  int gi = pos < S_ ? pos : S_-1;
  int tok = ids[b*S_ + gi];
  bool isa = (p==0);
  draft[idx] = isa ? tok : MASKID_;
  if (!isa){
    int rc = (idx >> 4)*15 + (p - 1);   // compact row index (pos always < S)
    lab2[rc] = tok;
  }
}

// ---------------- fused prep: hcat + weight converts + embedding gather ----------------
__global__ void k_prep(const float* __restrict__ hs,
    const float* __restrict__ fcw, const float* __restrict__ wq, const float* __restrict__ wk,
    const float* __restrict__ wv, const float* __restrict__ wo, const float* __restrict__ lmw,
    const float* __restrict__ et, const int* __restrict__ ids, const int* __restrict__ anch,
    ushort* __restrict__ hc, ushort* __restrict__ fcW, ushort* __restrict__ Wqkv,
    ushort* __restrict__ woW, ushort* __restrict__ lmW, ushort* __restrict__ emb){
  int idx = blockIdx.x*256 + threadIdx.x;
  const float* src; ushort* dst; size_t so, doff;
  if (idx < 1572864){
    int f8 = idx % 384; int row = idx / 384;
    int b = row >> 11, s = row & (S_-1);
    int f0 = f8*8, l = f0 >> 10, d = f0 & 1023;
    src = hs; so = (((size_t)l*B_ + b)*S_ + s)*D_ + d;
    dst = hc; doff = (size_t)row*3072 + f0;
  } else if (idx < 6586368){
    int i = idx - 1572864;
    int j;
    if (i < 393216){ src = fcw; dst = fcW; j = i; }
    else if (i < 524288){ src = wq;  dst = Wqkv;                    j = i - 393216; }
    else if (i < 655360){ src = wk;  dst = Wqkv + (size_t)1048576;  j = i - 524288; }
    else if (i < 786432){ src = wv;  dst = Wqkv + (size_t)2097152;  j = i - 655360; }
    else if (i < 917504){ src = wo;  dst = woW;                     j = i - 786432; }
    else               { src = lmw; dst = lmW;                     j = i - 917504; }
    so = (size_t)j*8; doff = (size_t)j*8;
  } else if (idx < 7110656){
    int j = idx - 6586368;
    int row = j >> 7, c = (j & 127)*8;
    int b = row >> 11, i = row & (Q_-1);
    int p = i & 15;
    int a = anch[b*NA_ + (i>>4)];
    int pos = a + p;
    int gi = pos < S_ ? pos : S_-1;
    int tok = ids[b*S_ + gi];
    int id = (p==0) ? tok : MASKID_;
    src = et; so = (size_t)id*D_ + c;
    dst = emb; doff = (size_t)row*D_ + c;
  } else return;
  const float4* s4 = (const float4*)(src + so);
  float4 a = s4[0], b = s4[1];
  short8 u;
  u[0]=(short)f2bf(a.x); u[1]=(short)f2bf(a.y); u[2]=(short)f2bf(a.z); u[3]=(short)f2bf(a.w);
  u[4]=(short)f2bf(b.x); u[5]=(short)f2bf(b.y); u[6]=(short)f2bf(b.z); u[7]=(short)f2bf(b.w);
  *(short8*)(dst + doff) = u;
}

// ---------------- shared GEMM body: C(128x128 tile) = A(MxK) * B(NxK)^T ----------------
__device__ __forceinline__ void gemm_body(const ushort* __restrict__ A, const ushort* __restrict__ Bm,
    void* __restrict__ C, int N, int K, int bm, int bn, int OBF, ushort* lA, ushort* lB){
  const int lane = threadIdx.x & 63, w = threadIdx.x >> 6;
  const int l15 = lane & 15, g = lane >> 4;
  const int wm = w >> 1, wn = w & 1;
  f32x4 acc[4][4];
  #pragma unroll
  for (int a0=0;a0<4;++a0)
    #pragma unroll
    for (int a1=0;a1<4;++a1) acc[a0][a1] = f32x4{0.f,0.f,0.f,0.f};
  int rowS[2], kgS[2];
  #pragma unroll
  for (int i=0;i<2;++i){
    int o = w*1024 + i*4096 + lane*16;
    rowS[i] = o >> 6;
    kgS[i] = (((o>>4)&3) - (rowS[i]>>1)) & 3;
  }
  for (int k0 = 0; k0 < K; k0 += 32){
    #pragma unroll
    for (int i=0;i<2;++i){
      const ushort* sa = A + (size_t)(bm*128 + rowS[i])*K + k0 + kgS[i]*8;
      const ushort* sb = Bm + (size_t)(bn*128 + rowS[i])*K + k0 + kgS[i]*8;
      __builtin_amdgcn_global_load_lds((const __attribute__((address_space(1))) void*)sa,
          (__attribute__((address_space(3))) void*)((char*)lA + w*1024 + i*4096), 16, 0, 0);
      __builtin_amdgcn_global_load_lds((const __attribute__((address_space(1))) void*)sb,
          (__attribute__((address_space(3))) void*)((char*)lB + w*1024 + i*4096), 16, 0, 0);
    }
    __syncthreads();
    short8 af[4], bf[4];
    #pragma unroll
    for (int mf=0;mf<4;++mf){
      int rr = wm*64 + mf*16 + l15;
      af[mf] = *(const short8*)((const char*)lA + rr*64 + (((g + (rr>>1))&3)*16));
    }
    #pragma unroll
    for (int nf=0;nf<4;++nf){
      int rr = wn*64 + nf*16 + l15;
      bf[nf] = *(const short8*)((const char*)lB + rr*64 + (((g + (rr>>1))&3)*16));
    }
    #pragma unroll
    for (int mf=0;mf<4;++mf)
      #pragma unroll
      for (int nf=0;nf<4;++nf)
        acc[mf][nf] = mfma16(af[mf], bf[nf], acc[mf][nf]);
    __syncthreads();
  }
  #pragma unroll
  for (int mf=0;mf<4;++mf)
  #pragma unroll
  for (int nf=0;nf<4;++nf){
    int row0 = bm*128 + wm*64 + mf*16 + g*4;
    int col  = bn*128 + wn*64 + nf*16 + l15;
    #pragma unroll
    for (int r=0;r<4;++r){
      if (OBF) ((ushort*)C)[(size_t)(row0+r)*N + col] = f2bf(acc[mf][nf][r]);
      else     ((float*)C)[(size_t)(row0+r)*N + col] = acc[mf][nf][r];
    }
  }
}

template<int OBF>
__global__ __launch_bounds__(256) void k_gemm(const ushort* __restrict__ A, const ushort* __restrict__ Bm,
                       void* __restrict__ C, int N, int K){
  __shared__ ushort lA[128*32];
  __shared__ ushort lB[128*32];
  gemm_body(A, Bm, C, N, K, blockIdx.x, blockIdx.y, OBF, lA, lB);
}

// fc GEMM (256 blocks) + qkv GEMM (768 blocks) merged: balanced (256*96 == 768*32 iters)
__global__ __launch_bounds__(256) void k_fcqkv(const ushort* __restrict__ hcat, const ushort* __restrict__ fcW,
    ushort* __restrict__ ctx, const ushort* __restrict__ emb, const ushort* __restrict__ Wqkv,
    ushort* __restrict__ C1){
  __shared__ ushort lA[128*32];
  __shared__ ushort lB[128*32];
  int bid = blockIdx.x;
  if (bid < 256){
    gemm_body(hcat, fcW, ctx, 1024, 3072, bid & 31, bid >> 5, 1, lA, lB);
  } else {
    int t = bid - 256;
    gemm_body(emb, Wqkv, C1, 3072, 1024, t & 31, t >> 5, 1, lA, lB);
  }
}

// ---------------- lm_head bf16 GEMM with fused softmax/argmax epilogue ----------------
// r10-proven kernel, FROZEN: 2-barrier BK=32 m97 structure, 0-conflict slot rotation,
// compact 3840 rows (bm>=30 exits; 32-wide grid keeps bm%8<->XCD A-tile pinning).
__global__ __launch_bounds__(256) void k_lmgemm(const ushort* __restrict__ A, const ushort* __restrict__ Bm,
    float* __restrict__ pm, float* __restrict__ pl, int* __restrict__ pbi){
  __shared__ ushort lA[128*32];
  __shared__ ushort lB[128*32];
  const int bm = blockIdx.x, bn = blockIdx.y;
  if (bm >= 30) return;
  const int lane = threadIdx.x & 63, w = threadIdx.x >> 6;
  const int l15 = lane & 15, g = lane >> 4;
  const int wm = w >> 1, wn = w & 1;
  f32x4 acc[4][4];
  #pragma unroll
  for (int a0=0;a0<4;++a0)
    #pragma unroll
    for (int a1=0;a1<4;++a1) acc[a0][a1] = f32x4{0.f,0.f,0.f,0.f};
  int rowS[2], kgS[2];
  #pragma unroll
  for (int i=0;i<2;++i){
    int o = w*1024 + i*4096 + lane*16;
    rowS[i] = o >> 6;
    kgS[i] = (((o>>4)&3) - (rowS[i]>>1)) & 3;
  }
  for (int k0 = 0; k0 < 1024; k0 += 32){
    #pragma unroll
    for (int i=0;i<2;++i){
      const ushort* sa = A + (size_t)(bm*128 + rowS[i])*1024 + k0 + kgS[i]*8;
      const ushort* sb = Bm + (size_t)(bn*128 + rowS[i])*1024 + k0 + kgS[i]*8;
      __builtin_amdgcn_global_load_lds((const __attribute__((address_space(1))) void*)sa,
          (__attribute__((address_space(3))) void*)((char*)lA + w*1024 + i*4096), 16, 0, 0);
      __builtin_amdgcn_global_load_lds((const __attribute__((address_space(1))) void*)sb,
          (__attribute__((address_space(3))) void*)((char*)lB + w*1024 + i*4096), 16, 0, 0);
    }
    __syncthreads();
    short8 af[4], bfr[4];
    #pragma unroll
    for (int mf=0;mf<4;++mf){
      int rr = wm*64 + mf*16 + l15;
      af[mf] = *(const short8*)((const char*)lA + rr*64 + (((g + (rr>>1))&3)*16));
    }
    #pragma unroll
    for (int nf=0;nf<4;++nf){
      int rr = wn*64 + nf*16 + l15;
      bfr[nf] = *(const short8*)((const char*)lB + rr*64 + (((g + (rr>>1))&3)*16));
    }
    #pragma unroll
    for (int mf=0;mf<4;++mf)
      #pragma unroll
      for (int nf=0;nf<4;++nf)
        acc[mf][nf] = mfma16(af[mf], bfr[nf], acc[mf][nf]);
    __syncthreads();
  }
  // epilogue: per-row stats over this wave's 64 columns; slice = bn*2+wn
  const int colb = bn*128 + wn*64 + l15;
  #pragma unroll
  for (int mf=0;mf<4;++mf){
    #pragma unroll
    for (int r=0;r<4;++r){
      float s0 = acc[mf][0][r], s1 = acc[mf][1][r], s2 = acc[mf][2][r], s3 = acc[mf][3][r];
      float M = rmax16(fmaxf(fmaxf(s0,s1), fmaxf(s2,s3)));
      float lsum = rsum16(__expf(s0-M) + __expf(s1-M) + __expf(s2-M) + __expf(s3-M));
      int ci = 0x7fffffff;
      if (s3 == M) ci = colb+48;
      if (s2 == M) ci = colb+32;
      if (s1 == M) ci = colb+16;
      if (s0 == M) ci = colb;
      #pragma unroll
      for (int msk=1; msk<16; msk<<=1){
        int oi = __shfl_xor(ci, msk);
        ci = oi < ci ? oi : ci;
      }
      if (l15 == 0){
        int row = bm*128 + wm*64 + mf*16 + g*4 + r;
        size_t pidx = (size_t)(bn*2 + wn)*NRC_ + row;
        pm[pidx] = M; pl[pidx] = lsum; pbi[pidx] = ci;
      }
    }
  }
}

// ---------------- fused RoPE scatter (draft + ctx) and vT pad-zero ----------------
__global__ void k_ropeall(const ushort* __restrict__ C1, const ushort* __restrict__ C2,
    const int* __restrict__ posf, ushort* __restrict__ qb, ushort* __restrict__ kb,
    ushort* __restrict__ vT){
  int idx = blockIdx.x*256 + threadIdx.x;
  if (idx < 2097152){
    int d2 = idx & 63, h = (idx>>6)&7, i = (idx>>9)&(Q_-1), b = idx>>20;
    int row = b*Q_ + i;
    int pos = posf[row];
    float inv = __expf(-(float)d2 * 0.14391156831212787f); // ln(10000)/64
    float ang = (float)pos * inv;
    float sn, cs; __sincosf(ang, &sn, &cs);
    const ushort* cr = C1 + (size_t)row*3072 + h*DH_ + d2;
    float x1 = bf2f(cr[0]), x2 = bf2f(cr[64]);
    size_t qo = (size_t)row*D_ + h*DH_ + d2;
    qb[qo] = f2bf(x1*cs - x2*sn); qb[qo+64] = f2bf(x1*sn + x2*cs);
    x1 = bf2f(cr[1024]); x2 = bf2f(cr[1088]);
    size_t ko = ((size_t)(b*KV_ + S_ + i))*D_ + h*DH_ + d2;
    kb[ko] = f2bf(x1*cs - x2*sn); kb[ko+64] = f2bf(x1*sn + x2*cs);
    x1 = bf2f(cr[2048]); x2 = bf2f(cr[2112]);
    size_t vo = ((size_t)((b*H_ + h)*DH_ + d2))*KVP_ + (S_ + i);
    vT[vo] = f2bf(x1); vT[vo + (size_t)64*KVP_] = f2bf(x2);
  } else if (idx < 4194304){
    int t = idx - 2097152;
    int d2 = t & 63, h = (t>>6)&7, i = (t>>9)&(S_-1), b = t>>20;
    int row = b*S_ + i;
    float inv = __expf(-(float)d2 * 0.14391156831212787f);
    float ang = (float)i * inv;
    float sn, cs; __sincosf(ang, &sn, &cs);
    const ushort* cr = C2 + (size_t)row*2048 + h*DH_ + d2;
    float x1 = bf2f(cr[0]), x2 = bf2f(cr[64]);
    size_t ko = ((size_t)(b*KV_ + i))*D_ + h*DH_ + d2;
    kb[ko] = f2bf(x1*cs - x2*sn); kb[ko+64] = f2bf(x1*sn + x2*cs);
    x1 = bf2f(cr[1024]); x2 = bf2f(cr[1088]);
    size_t vo = ((size_t)((b*H_ + h)*DH_ + d2))*KVP_ + i;
    vT[vo] = f2bf(x1); vT[vo + (size_t)64*KVP_] = f2bf(x2);
  } else if (idx < 4259840){
    int t = idx - 4194304;
    int row = t >> 5, c = t & 31;
    vT[(size_t)row*KVP_ + 4096 + c] = 0;
  }
}

// ---------------- block-sparse flash attention, split-KV, KVBLK=64 ----------------
__global__ __launch_bounds__(512) void k_attn(const ushort* __restrict__ qb, const ushort* __restrict__ kb,
    const ushort* __restrict__ vT, const int* __restrict__ anch, ushort* __restrict__ ao){
  __shared__ ushort pbuf[8][16*72];
  __shared__ float mrg[4][16][128];
  __shared__ float mml[4][2][16];
  const int lane = threadIdx.x & 63, w = threadIdx.x >> 6;
  const int l15 = lane & 15, g = lane >> 4;
  const int wt = w & 3, half = w >> 2;
  const int gi = blockIdx.x;
  const int logical = (gi & 7)*64 + (gi >> 3);   // bijective XCD grouping (512 blocks)
  const int b = logical >> 8, h = (logical >> 5) & 7;
  const int qblk = (logical & 31)*4 + wt;
  const int anc = anch[b*NA_ + qblk];
  ushort* pb = pbuf[w];
  short8 aq[4];
  {
    const ushort* qr = qb + ((size_t)(b*Q_ + qblk*16 + l15))*D_ + h*DH_ + g*8;
    #pragma unroll
    for (int kc=0;kc<4;++kc) aq[kc] = *(const short8*)(qr + kc*32);
  }
  f32x4 o[8];
  #pragma unroll
  for (int cc=0;cc<8;++cc) o[cc] = f32x4{0.f,0.f,0.f,0.f};
  float m[4] = {-1e30f,-1e30f,-1e30f,-1e30f};
  float sl[4] = {0.f,0.f,0.f,0.f};
  const float SC = 0.08838834764831845f; // 1/sqrt(128)
  const ushort* vbase = vT + ((size_t)((b*H_ + h)*DH_))*KVP_;

  auto process = [&](int kv0, int limit){
    const int nk = limit - kv0;
    f32x4 sc[4];
    #pragma unroll
    for (int f=0;f<4;++f) sc[f] = f32x4{0.f,0.f,0.f,0.f};
    const ushort* kr = kb + ((size_t)(b*KV_ + kv0 + l15))*D_ + h*DH_ + g*8;
    #pragma unroll
    for (int f=0;f<4;++f){
      if (f*16 < nk){
        const ushort* krf = kr + (size_t)(f*16)*D_;
        #pragma unroll
        for (int kc=0;kc<4;++kc){
          short8 bk = *(const short8*)(krf + kc*32);
          sc[f] = mfma16(aq[kc], bk, sc[f]);
        }
      }
    }
    #pragma unroll
    for (int r=0;r<4;++r){
      float s0 = (kv0 + l15      < limit) ? sc[0][r]*SC : -1e30f;
      float s1 = (kv0 + 16 + l15 < limit) ? sc[1][r]*SC : -1e30f;
      float s2 = (kv0 + 32 + l15 < limit) ? sc[2][r]*SC : -1e30f;
      float s3 = (kv0 + 48 + l15 < limit) ? sc[3][r]*SC : -1e30f;
      float cm = rmax16(fmaxf(fmaxf(s0,s1), fmaxf(s2,s3)));
      float mn = fmaxf(m[r], cm);
      float esc = __expf(m[r] - mn);
      float p0 = __expf(s0 - mn), p1 = __expf(s1 - mn);
      float p2 = __expf(s2 - mn), p3 = __expf(s3 - mn);
      float rs = rsum16(p0 + p1 + p2 + p3);
      sl[r] = sl[r]*esc + rs;
      m[r] = mn;
      #pragma unroll
      for (int cc=0;cc<8;++cc) o[cc][r] *= esc;
      int q = g*4 + r;
      pb[q*72 + l15]      = f2bf(p0);
      pb[q*72 + 16 + l15] = f2bf(p1);
      pb[q*72 + 32 + l15] = f2bf(p2);
      pb[q*72 + 48 + l15] = f2bf(p3);
    }
    asm volatile("s_waitcnt lgkmcnt(0)" ::: "memory");
    __builtin_amdgcn_sched_barrier(0);
    const ushort* pr = pb + l15*72 + g*8;
    short8 pa0 = *(const short8*)pr;
    const ushort* vr = vbase + kv0 + g*8;
    #pragma unroll
    for (int cc=0;cc<8;++cc){
      short8 bv = *(const short8*)(vr + (size_t)(cc*16 + l15)*KVP_);
      o[cc] = mfma16(pa0, bv, o[cc]);
    }
    if (nk > 32){
      short8 pa1 = *(const short8*)(pr + 32);
      const ushort* vr2 = vr + 32;
      #pragma unroll
      for (int cc=0;cc<8;++cc){
        short8 bv = *(const short8*)(vr2 + (size_t)(cc*16 + l15)*KVP_);
        o[cc] = mfma16(pa1, bv, o[cc]);
      }
    }
  };
  for (int kv0 = half*64; kv0 < anc; kv0 += 128) process(kv0, anc);
  if (half == 1){
    int kv0 = S_ + qblk*16;
    process(kv0, kv0 + 16);
    #pragma unroll
    for (int cc=0;cc<8;++cc)
      #pragma unroll
      for (int r=0;r<4;++r)
        mrg[wt][g*4+r][cc*16+l15] = o[cc][r];
    if (l15 == 0){
      #pragma unroll
      for (int r=0;r<4;++r){ mml[wt][0][g*4+r] = m[r]; mml[wt][1][g*4+r] = sl[r]; }
    }
  }
  __syncthreads();
  if (half == 0){
    #pragma unroll
    for (int r=0;r<4;++r){
      float m1 = mml[wt][0][g*4+r], l1 = mml[wt][1][g*4+r];
      float mn = fmaxf(m[r], m1);
      float e0 = __expf(m[r] - mn), e1 = __expf(m1 - mn);
      float lm = sl[r]*e0 + l1*e1;
      int q = g*4 + r;
      #pragma unroll
      for (int cc=0;cc<8;++cc){
        float val = (o[cc][r]*e0 + mrg[wt][q][cc*16+l15]*e1) / lm;
        ao[((size_t)(b*Q_ + qblk*16 + q))*D_ + h*DH_ + cc*16 + l15] = f2bf(val);
      }
    }
  }
}

// ---------------- residual + RMSNorm -> compact hb + fused label logit ----------------
__global__ __launch_bounds__(256) void k_rms(const float* __restrict__ wo_out, const float* __restrict__ et,
    const int* __restrict__ draft, const float* __restrict__ nw, const int* __restrict__ lab2,
    const float* __restrict__ lmw, ushort* __restrict__ hb, float* __restrict__ plbl){
  const int rc = blockIdx.x, tid = threadIdx.x;
  const int row = (rc/15)*16 + rc%15 + 1;     // inverse compact map (p = rc%15+1)
  const int lane = tid & 63, w = tid >> 6;
  const float* wr = wo_out + (size_t)row*D_;
  const float* er = et + (size_t)draft[row]*D_;
  float v[4]; float ss = 0.f;
  #pragma unroll
  for (int j=0;j<4;++j){
    int d = tid + j*256;
    v[j] = er[d] + wr[d];
    ss += v[j]*v[j];
  }
  #pragma unroll
  for (int msk=1; msk<64; msk<<=1) ss += __shfl_xor(ss, msk);
  __shared__ float red[4];
  __shared__ float red2[4];
  if (lane == 0) red[w] = ss;
  __syncthreads();
  float tot = red[0]+red[1]+red[2]+red[3];
  float rs = rsqrtf(tot*(1.f/1024.f) + 1e-6f);
  const float* lr = lmw + (size_t)lab2[rc]*D_;
  float sdot = 0.f;
  #pragma unroll
  for (int j=0;j<4;++j){
    int d = tid + j*256;
    float x = v[j]*rs*nw[d];
    hb[(size_t)rc*D_ + d] = f2bf(x);
    sdot += x * lr[d];
  }
  #pragma unroll
  for (int msk=1; msk<64; msk<<=1) sdot += __shfl_xor(sdot, msk);
  if (lane == 0) red2[w] = sdot;
  __syncthreads();
  if (tid == 0) plbl[rc] = red2[0]+red2[1]+red2[2]+red2[3];
}

// ---------------- combine: one wave per compact row, lane-strided over NP_ slices ----------------
__global__ __launch_bounds__(256) void k_combine(const float* __restrict__ pm, const float* __restrict__ pl,
    const int* __restrict__ pbi, const float* __restrict__ plbl,
    const int* __restrict__ lab2, float* __restrict__ pblk){
  const int lane = threadIdx.x & 63, w = threadIdx.x >> 6;
  const int row = blockIdx.x*4 + w;
  float M = -1e30f, Lx = 0.f;
  float bv = -1e30f; int bi = 0x7fffffff;
  for (int s = lane; s < NP_; s += 64){
    size_t idx = (size_t)s*NRC_ + row;
    float mm = pm[idx], ll = pl[idx];
    float Mn = fmaxf(M, mm);
    Lx = Lx*__expf(M-Mn) + ll*__expf(mm-Mn);
    M = Mn;
    int ii = pbi[idx];
    if (mm > bv || (mm == bv && ii < bi)){ bv = mm; bi = ii; }
  }
  #pragma unroll
  for (int msk=1; msk<64; msk<<=1){
    float Mo = __shfl_xor(M, msk), Lo = __shfl_xor(Lx, msk);
    float bvo = __shfl_xor(bv, msk); int bio = __shfl_xor(bi, msk);
    float Mn = fmaxf(M, Mo);
    Lx = Lx*__expf(M-Mn) + Lo*__expf(Mo-Mn);
    M = Mn;
    if (bvo > bv || (bvo == bv && bio < bi)){ bv = bvo; bi = bio; }
  }
  __shared__ float red[4][4];
  if (lane == 0){
    float logZ = M + logf(Lx);
    float lb = plbl[row];
    int lab = lab2[row];
    float wgt = __expf(-(float)(row%15)*(1.f/7.f));   // p = row%15+1
    float nll = logZ - lb;
    red[w][0] = wgt*nll;
    red[w][1] = wgt;
    red[w][2] = (bi == lab) ? 1.f : 0.f;
    red[w][3] = 1.f;
  }
  __syncthreads();
  if (threadIdx.x == 0){
    float s0=0,s1=0,s2=0,s3=0;
    for (int i=0;i<4;++i){ s0+=red[i][0]; s1+=red[i][1]; s2+=red[i][2]; s3+=red[i][3]; }
    pblk[blockIdx.x*4+0]=s0; pblk[blockIdx.x*4+1]=s1; pblk[blockIdx.x*4+2]=s2; pblk[blockIdx.x*4+3]=s3;
  }
}

__global__ void k_final(const float* __restrict__ pblk, float* __restrict__ out){
  const int t = threadIdx.x;
  float s0=0,s1=0,s2=0,s3=0;
  for (int i=t; i<960; i+=256){
    const float4 v = *(const float4*)(pblk + i*4);
    s0+=v.x; s1+=v.y; s2+=v.z; s3+=v.w;
  }
  #pragma unroll
  for (int msk=1; msk<64; msk<<=1){
    s0+=__shfl_xor(s0,msk); s1+=__shfl_xor(s1,msk);
    s2+=__shfl_xor(s2,msk); s3+=__shfl_xor(s3,msk);
  }
  __shared__ float red[4][4];
  int lane = t & 63, w = t >> 6;
  if (lane==0){ red[w][0]=s0; red[w][1]=s1; red[w][2]=s2; red[w][3]=s3; }
  __syncthreads();
  if (t==0){
    float a0=red[0][0]+red[1][0]+red[2][0]+red[3][0];
    float a1=red[0][1]+red[1][1]+red[2][1]+red[3][1];
    float a2=red[0][2]+red[1][2]+red[2][2]+red[3][2];
    float a3=red[0][3]+red[1][3]+red[2][3]+red[3][3];
    out[0]=a0/fmaxf(a1,1e-6f);
    out[1]=a2/fmaxf(a3,1.f);
  }
}

extern "C" void kernel_launch(void* const* d_in, const int* in_sizes, int n_in,
                              void* d_out, int out_size, void* d_ws, size_t ws_size,
                              hipStream_t stream){
  const int*   ids  = (const int*)d_in[0];
  const float* hs   = (const float*)d_in[1];
  const int*   anch = (const int*)d_in[2];
  const float* lmw  = (const float*)d_in[3];
  const float* nw   = (const float*)d_in[4];
  const float* fcw  = (const float*)d_in[5];
  const float* et   = (const float*)d_in[6];
  const float* wq   = (const float*)d_in[7];
  const float* wk   = (const float*)d_in[8];
  const float* wvp  = (const float*)d_in[9];
  const float* wo   = (const float*)d_in[10];
  float* out = (float*)d_out;
  (void)in_sizes; (void)n_in; (void)out_size; (void)ws_size;

  char* ws = (char*)d_ws;
  size_t off = 0;
  auto alloc = [&](size_t bytes)->char*{ char* p = ws + off; off = (off + bytes + 255) & ~(size_t)255; return p; };
  ushort* fcW   = (ushort*)alloc((size_t)1024*3072*2);
  ushort* Wqkv  = (ushort*)alloc((size_t)3072*1024*2);
  ushort* woW   = (ushort*)alloc((size_t)1024*1024*2);
  ushort* lmW   = (ushort*)alloc((size_t)V_*1024*2);
  ushort* ctx   = (ushort*)alloc((size_t)4096*1024*2);   // later: pm overlay (7.68MB)
  ushort* emb   = (ushort*)alloc((size_t)4096*1024*2);   // later: pl overlay
  ushort* hcat  = (ushort*)alloc((size_t)4096*3072*2);   // reused as C1, later pbi overlay
  ushort* C1 = hcat;
  ushort* C2    = (ushort*)alloc((size_t)4096*2048*2);   // reused as wo_out (f32)
  float* wo_out = (float*)C2;
  ushort* qbuf  = (ushort*)alloc((size_t)4096*1024*2);
  ushort* kbuf  = (ushort*)alloc((size_t)B_*KV_*1024*2);
  ushort* vT    = (ushort*)alloc((size_t)B_*H_*DH_*KVP_*2);
  ushort* ao    = (ushort*)alloc((size_t)4096*1024*2);
  ushort* hb    = (ushort*)alloc((size_t)NRC_*1024*2);
  int* draft  = (int*)alloc(4096*4);
  int* lab2   = (int*)alloc(NRC_*4);
  int* posf   = (int*)alloc(4096*4);
  float* plbl = (float*)alloc(NRC_*4);
  float* pblk = (float*)alloc(960*4*4);
  // partial arrays (each NP_*NRC_*4 = 7.68 MB) overlay buffers dead by lm_head time,
  // fully rewritten by k_lmgemm every call (tripwire-safe: no stale reads possible)
  float* pm  = (float*)ctx;
  float* pl  = (float*)emb;
  int*   pbi = (int*)hcat;

  k_meta<<<16,256,0,stream>>>(ids, anch, draft, lab2, posf);
  k_prep<<<27776,256,0,stream>>>(hs, fcw, wq, wk, wvp, wo, lmw, et, ids, anch,
                                 hcat, fcW, Wqkv, woW, lmW, emb);
  k_fcqkv<<<1024,256,0,stream>>>(hcat, fcW, ctx, emb, Wqkv, C1);
  k_gemm<1><<<dim3(32,16),256,0,stream>>>(ctx, Wqkv + (size_t)1024*1024, C2, 2048, 1024);
  k_ropeall<<<16640,256,0,stream>>>(C1, C2, posf, qbuf, kbuf, vT);
  k_attn<<<512,512,0,stream>>>(qbuf, kbuf, vT, anch, ao);
  k_gemm<0><<<dim3(32,8),256,0,stream>>>(ao, woW, wo_out, 1024, 1024);
  k_rms<<<NRC_,256,0,stream>>>(wo_out, et, draft, nw, lab2, lmw, hb, plbl);
  k_lmgemm<<<dim3(32,250),256,0,stream>>>(hb, lmW, pm, pl, pbi);
  k_combine<<<960,256,0,stream>>>(pm, pl, pbi, plbl, lab2, pblk);
  k_final<<<1,256,0,stream>>>(pblk, out);
}